// Round 4
// baseline (603.144 us; speedup 1.0000x reference)
//
#include <hip/hip_runtime.h>
#include <math.h>

#define Bn 4
#define Ln 1024
#define Sn 1024
#define Hn 8
#define En 64

typedef __attribute__((ext_vector_type(4))) float f32x4;
typedef __attribute__((ext_vector_type(8))) _Float16 h16x8;
typedef __attribute__((ext_vector_type(4))) _Float16 h16x4;

__device__ __forceinline__ float frcp(float x) { return __builtin_amdgcn_rcpf(x); }
__device__ __forceinline__ float fexp2(float x) {
    float r; asm("v_exp_f32 %0, %1" : "=v"(r) : "v"(x)); return r;
}
__device__ __forceinline__ float flog2(float x) {
    float r; asm("v_log_f32 %0, %1" : "=v"(r) : "v"(x)); return r;
}

// ---------------------------------------------------------------------------
// prep: split Q,K fp32 -> f16 hi/lo, fragment-major layout
//   [bh][tile][kq][row][8]  (kq = 8-half k-chunk 0..7, row 0..63 in tile)
// V -> f16 transposed tiles in the same fragment-major layout (rows = d,
// k-chunks over local s).
// ---------------------------------------------------------------------------
__global__ __launch_bounds__(256) void prep(
    const float* __restrict__ Q, const float* __restrict__ K,
    const float* __restrict__ V,
    _Float16* __restrict__ Qh, _Float16* __restrict__ Ql,
    _Float16* __restrict__ Kh, _Float16* __restrict__ Kl,
    _Float16* __restrict__ Vt) {
    __shared__ float vlds[64][69];
    const int st = blockIdx.x;   // s-tile 0..15
    const int bh = blockIdx.y;   // 0..31
    const int b = bh >> 3, h = bh & 7;
    const int tid = threadIdx.x;
    const int s0 = st * 64;

#pragma unroll
    for (int i = 0; i < 4; ++i) {
        int idx = tid + 256 * i;     // 0..1023
        int r = idx >> 4;            // row 0..63
        int c4 = (idx & 15) << 2;    // e 0,4..60
        size_t gin = (((size_t)b * Ln + s0 + r) * Hn + h) * En + c4;
        f32x4 qv = *(const f32x4*)(Q + gin);
        f32x4 kv = *(const f32x4*)(K + gin);
        f32x4 vv = *(const f32x4*)(V + gin);
        vlds[r][c4 + 0] = vv.x; vlds[r][c4 + 1] = vv.y;
        vlds[r][c4 + 2] = vv.z; vlds[r][c4 + 3] = vv.w;
        h16x4 qh4, ql4, kh4, kl4;
#pragma unroll
        for (int j = 0; j < 4; ++j) {
            float x = qv[j];
            _Float16 hx = (_Float16)x;
            qh4[j] = hx; ql4[j] = (_Float16)(x - (float)hx);
            float y = kv[j];
            _Float16 hy = (_Float16)y;
            kh4[j] = hy; kl4[j] = (_Float16)(y - (float)hy);
        }
        size_t ob = ((((size_t)bh * 16 + st) * 8 + (c4 >> 3)) * 64 + r) * 8 + (c4 & 7);
        *(h16x4*)(Qh + ob) = qh4; *(h16x4*)(Ql + ob) = ql4;
        *(h16x4*)(Kh + ob) = kh4; *(h16x4*)(Kl + ob) = kl4;
    }
    __syncthreads();
    // transposed V tile, fragment-major: rows = d, k-chunks over local s
#pragma unroll
    for (int i = 0; i < 4; ++i) {
        int idx = tid + 256 * i;
        int d = idx >> 4;            // 0..63
        int sg = (idx & 15) << 2;    // 0..60
        h16x4 v4;
#pragma unroll
        for (int j = 0; j < 4; ++j) v4[j] = (_Float16)vlds[sg + j][d];
        size_t ob = ((((size_t)bh * 16 + st) * 8 + (sg >> 3)) * 64 + d) * 8 + (sg & 7);
        *(h16x4*)(Vt + ob) = v4;
    }
}

// ---------------------------------------------------------------------------
// prep2: batch-independent mask precompute.
//   mh[h][l][s] = 0.125 * sigmoid((log(u+eps)-log(1-u+eps)+phi)/tau) * hard
// ---------------------------------------------------------------------------
__global__ __launch_bounds__(256) void prep2(
    const float* __restrict__ phi, const float* __restrict__ u,
    const float* __restrict__ hard, const float* __restrict__ p_lt,
    _Float16* __restrict__ mh) {
    const float tau = fminf(fmaxf(expf(p_lt[0]), 0.1f), 5.0f);
    const float itau = 1.0f / tau;
    const size_t base = ((size_t)blockIdx.x * 256 + threadIdx.x) * 8;
    const size_t ls = base & (size_t)(Ln * Sn - 1);
    f32x4 ph0 = *(const f32x4*)(phi + base);
    f32x4 ph1 = *(const f32x4*)(phi + base + 4);
    f32x4 uu0 = *(const f32x4*)(u + base);
    f32x4 uu1 = *(const f32x4*)(u + base + 4);
    f32x4 hm0 = *(const f32x4*)(hard + ls);
    f32x4 hm1 = *(const f32x4*)(hard + ls + 4);
    h16x8 o;
#pragma unroll
    for (int j = 0; j < 4; ++j) {
        float z = (__logf((uu0[j] + 1e-8f) * frcp(1.0f - uu0[j] + 1e-8f)) + ph0[j]) * itau;
        float m = frcp(1.0f + __expf(-z));
        o[j] = (_Float16)(0.125f * m * hm0[j]);
    }
#pragma unroll
    for (int j = 0; j < 4; ++j) {
        float z = (__logf((uu1[j] + 1e-8f) * frcp(1.0f - uu1[j] + 1e-8f)) + ph1[j]) * itau;
        float m = frcp(1.0f + __expf(-z));
        o[4 + j] = (_Float16)(0.125f * m * hm1[j]);
    }
    *(h16x8*)(mh + base) = o;
}

// ---------------------------------------------------------------------------
// fused: barrier-free, XCD-pinned. Grid = flat 2048; bijective swizzle
// work = (f&7)*256 + (f>>3) pins head h = XCD (all 4 batches, 16 l-tiles x
// 4 s-quarters). Per-XCD L2 working set: 4 bh x 5 arrays (2.5 MB) + mh[h]
// (2 MB) -> fragments are L2 hits. 8 blocks/CU (launch_bounds(256,8)),
// LDS 9 KB, VGPR <= 64 -> 32 waves/CU.
// Per block: 4 chunks of 64 s; QK f16-split MFMA -> elementwise -> PV MFMA.
// ---------------------------------------------------------------------------
__global__ __launch_bounds__(256, 8) void fused_lie(
    const _Float16* __restrict__ Qh, const _Float16* __restrict__ Ql,
    const _Float16* __restrict__ Kh, const _Float16* __restrict__ Kl,
    const _Float16* __restrict__ Vt, const _Float16* __restrict__ mh,
    const float* __restrict__ p_lg, const float* __restrict__ p_ltc,
    float* __restrict__ Aout, float* __restrict__ Vout,
    float* __restrict__ entOut) {
    __shared__ __align__(16) _Float16 plds[4][16 * 72];

    // ---- XCD-pinned work decode (8 XCDs, flat%8 = XCD assumption) ----
    const int f = blockIdx.x;                 // 0..2047
    const int work = (f & 7) * 256 + (f >> 3);
    const int h = work >> 8;                  // 0..7  == XCD
    const int rem = work & 255;
    const int b = rem >> 6;                   // 0..3
    const int tile = rem & 63;
    const int lt = tile >> 2;                 // 0..15
    const int sq = tile & 3;                  // s-quarter 0..3
    const int bh = b * Hn + h;
    const int tid = threadIdx.x;
    const int w = tid >> 6;
    const int lane = tid & 63;
    const int q = lane >> 4;
    const int n = lane & 15;
    const int l0 = lt * 64;

    const float gain = fminf(fmaxf(expf(p_lg[0]), 1e-3f), 1000.0f);
    const float tauc = fminf(fmaxf(expf(p_ltc[0]), 1e-3f), 10.0f);
    const float c2l = 2.0f * gain / tauc * 1.44269504f;   // exp(c2*x) = exp2(c2l*x)

    // A-side fragments (registers): rows l0+w*16+n, k-chunk q+4*kh
    h16x8 QAh[2], QAl[2], KAh[2], KAl[2];
    {
        const size_t ab = (((size_t)bh * 16 + lt) * 8) * 512 + (size_t)(w * 16 + n) * 8;
#pragma unroll
        for (int kh = 0; kh < 2; ++kh) {
            size_t off = ab + (size_t)(q + 4 * kh) * 512;
            QAh[kh] = *(const h16x8*)(Qh + off);
            QAl[kh] = *(const h16x8*)(Ql + off);
            KAh[kh] = *(const h16x8*)(Kh + off);
            KAl[kh] = *(const h16x8*)(Kl + off);
        }
    }

    f32x4 accV[4];
#pragma unroll
    for (int i = 0; i < 4; ++i) accV[i] = (f32x4){0.f, 0.f, 0.f, 0.f};
    float entp[4] = {0.f, 0.f, 0.f, 0.f};

    const int lbase = l0 + w * 16 + q * 4;
    float* __restrict__ arow = Aout + (((size_t)b * Hn + h) * Ln + lbase) * (size_t)Sn;
    const _Float16* __restrict__ ment = mh + ((size_t)h * Ln + lbase) * (size_t)Sn;

    for (int stc = 0; stc < 4; ++stc) {
        const int st = sq * 4 + stc;
        const int s0 = st * 64;
        const size_t tb = (((size_t)bh * 16 + st) * 8) * 512;

        // ---- QK: acc1 = Q.K^T, acc2 = K.Q^T (f16 split, direct global B) ----
        f32x4 a1[4], a2[4];
#pragma unroll
        for (int i = 0; i < 4; ++i) {
            a1[i] = (f32x4){0.f, 0.f, 0.f, 0.f};
            a2[i] = (f32x4){0.f, 0.f, 0.f, 0.f};
        }
#pragma unroll
        for (int kh = 0; kh < 2; ++kh) {
            const size_t kqb = tb + (size_t)(q + 4 * kh) * 512;
#pragma unroll
            for (int sub = 0; sub < 4; ++sub) {
                const size_t off = kqb + (size_t)(sub * 16 + n) * 8;
                h16x8 KBh = *(const h16x8*)(Kh + off);
                h16x8 KBl = *(const h16x8*)(Kl + off);
                h16x8 QBh = *(const h16x8*)(Qh + off);
                h16x8 QBl = *(const h16x8*)(Ql + off);
                f32x4 x1 = a1[sub], x2 = a2[sub];
                x1 = __builtin_amdgcn_mfma_f32_16x16x32_f16(QAh[kh], KBh, x1, 0, 0, 0);
                x1 = __builtin_amdgcn_mfma_f32_16x16x32_f16(QAh[kh], KBl, x1, 0, 0, 0);
                x1 = __builtin_amdgcn_mfma_f32_16x16x32_f16(QAl[kh], KBh, x1, 0, 0, 0);
                x2 = __builtin_amdgcn_mfma_f32_16x16x32_f16(KAh[kh], QBh, x2, 0, 0, 0);
                x2 = __builtin_amdgcn_mfma_f32_16x16x32_f16(KAh[kh], QBl, x2, 0, 0, 0);
                x2 = __builtin_amdgcn_mfma_f32_16x16x32_f16(KAl[kh], QBh, x2, 0, 0, 0);
                a1[sub] = x1; a2[sub] = x2;
            }
        }

        // ---- elementwise chain (C-layout: row q*4+r, col sub*16+n) ----
#pragma unroll
        for (int sub = 0; sub < 4; ++sub) {
            const int s = s0 + sub * 16 + n;
#pragma unroll
            for (int r = 0; r < 4; ++r) {
                float mhv = (float)ment[(size_t)r * Sn + s];
                float cm = a1[sub][r] - a2[sub][r];
                // tanh(c1*cm) = 1 - 2/(exp2(c2l*cm)+1)
                float x = 1.0f - 2.0f * frcp(fexp2(c2l * cm) + 1.0f);
                // tanh-form gelu: x * sigmoid(1.5957691*(x + 0.044715 x^3))
                float t = x * fmaf(0.044715f * x, x, 1.0f);
                float g = x * frcp(1.0f + fexp2(-2.30221271f * t));
                float att = g * mhv;               // mh carries 0.125*m*hard
                arow[(size_t)r * Sn + s] = att;
                entp[r] += att * flog2(fmaxf(att, 1e-8f));
                plds[w][(q * 4 + r) * 72 + sub * 16 + n] = (_Float16)att;
            }
        }
        asm volatile("" ::: "memory");   // order plds writes before PV reads

        // ---- PV: accV += P . V (P A-frags from per-warp LDS, V^T global) ----
        {
            const _Float16* pw = &plds[w][0];
#pragma unroll
            for (int kh = 0; kh < 2; ++kh) {
                const size_t kqb = tb + (size_t)(q + 4 * kh) * 512;
                h16x8 Pf = *(const h16x8*)&pw[n * 72 + q * 8 + kh * 32];
#pragma unroll
                for (int sub = 0; sub < 4; ++sub) {
                    h16x8 Vf = *(const h16x8*)(Vt + kqb + (size_t)(sub * 16 + n) * 8);
                    accV[sub] = __builtin_amdgcn_mfma_f32_16x16x32_f16(Pf, Vf, accV[sub], 0, 0, 0);
                }
            }
        }
        asm volatile("" ::: "memory");   // order PV reads before next chunk's writes
    }

    // ---- epilogue: V partial sums via atomics (4 s-quarter blocks per l) ----
#pragma unroll
    for (int sub = 0; sub < 4; ++sub) {
#pragma unroll
        for (int r = 0; r < 4; ++r) {
            const int l = l0 + w * 16 + q * 4 + r;
            atomicAdd(Vout + (((size_t)b * Ln + l) * Hn + h) * En + sub * 16 + n, accV[sub][r]);
        }
    }
    // ---- entropy: quad-row reduce over 16 lanes, atomic partial (ln2 scale) ----
#pragma unroll
    for (int r = 0; r < 4; ++r) {
        float v = entp[r];
        v += __shfl_xor(v, 1);
        v += __shfl_xor(v, 2);
        v += __shfl_xor(v, 4);
        v += __shfl_xor(v, 8);
        if (n == 0) {
            atomicAdd(entOut + ((size_t)b * Hn + h) * Ln + lbase + r, -v * 0.69314718f);
        }
    }
}

extern "C" void kernel_launch(void* const* d_in, const int* in_sizes, int n_in,
                              void* d_out, int out_size, void* d_ws, size_t ws_size,
                              hipStream_t stream) {
    (void)in_sizes; (void)n_in; (void)ws_size; (void)out_size;

    const float* Q    = (const float*)d_in[0];   // (B,L,H,E)
    const float* K    = (const float*)d_in[1];   // (B,S,H,E)
    const float* Vv   = (const float*)d_in[2];   // (B,S,H,E)
    const float* phi  = (const float*)d_in[3];   // (H,L,S)
    const float* lg   = (const float*)d_in[4];
    const float* ltau = (const float*)d_in[5];
    const float* ltc  = (const float*)d_in[6];
    const float* hard = (const float*)d_in[7];   // (L,S)
    const float* u    = (const float*)d_in[8];   // (H,L,S)

    float* out  = (float*)d_out;
    float* Vout = out;                                 // B*L*H*E
    float* Aout = out + (size_t)Bn * Ln * Hn * En;     // B*H*L*S
    float* ent  = Aout + (size_t)Bn * Hn * Ln * Sn;    // B*H*L

    const size_t NE = (size_t)32 * 1024 * 64;          // 2.1M halves per array
    _Float16* Qh = (_Float16*)d_ws;
    _Float16* Ql = Qh + NE;
    _Float16* Kh = Ql + NE;
    _Float16* Kl = Kh + NE;
    _Float16* Vt = Kl + NE;
    _Float16* mh = Vt + NE;                            // H*L*S halves (16 MB)

    hipMemsetAsync(Vout, 0, (size_t)Bn * Ln * Hn * En * sizeof(float), stream);
    hipMemsetAsync(ent, 0, (size_t)Bn * Hn * Ln * sizeof(float), stream);
    prep<<<dim3(16, 32), 256, 0, stream>>>(Q, K, Vv, Qh, Ql, Kh, Kl, Vt);
    prep2<<<dim3(4096), 256, 0, stream>>>(phi, u, hard, ltau, mh);
    fused_lie<<<dim3(2048), 256, 0, stream>>>(Qh, Ql, Kh, Kl, Vt, mh,
                                              lg, ltc, Aout, Vout, ent);
}

// Round 5
// 366.088 us; speedup vs baseline: 1.6475x; 1.6475x over previous
//
#include <hip/hip_runtime.h>
#include <math.h>

#define Bn 4
#define Ln 1024
#define Sn 1024
#define Hn 8
#define En 64

typedef __attribute__((ext_vector_type(4))) float f32x4;
typedef __attribute__((ext_vector_type(8))) _Float16 h16x8;
typedef __attribute__((ext_vector_type(4))) _Float16 h16x4;

__device__ __forceinline__ float frcp(float x) { return __builtin_amdgcn_rcpf(x); }
__device__ __forceinline__ float fexp2(float x) {
    float r; asm("v_exp_f32 %0, %1" : "=v"(r) : "v"(x)); return r;
}
__device__ __forceinline__ float flog2(float x) {
    float r; asm("v_log_f32 %0, %1" : "=v"(r) : "v"(x)); return r;
}

// ---------------------------------------------------------------------------
// prep: split Q,K fp32 -> f16 hi/lo, fragment-major layout
//   [bh][tile][kq][row][8]  (kq = 8-half k-chunk 0..7, row 0..63 in tile)
// V -> f16 transposed tiles in the same fragment-major layout (rows = d,
// k-chunks over local s).
// ---------------------------------------------------------------------------
__global__ __launch_bounds__(256) void prep(
    const float* __restrict__ Q, const float* __restrict__ K,
    const float* __restrict__ V,
    _Float16* __restrict__ Qh, _Float16* __restrict__ Ql,
    _Float16* __restrict__ Kh, _Float16* __restrict__ Kl,
    _Float16* __restrict__ Vt) {
    __shared__ float vlds[64][69];
    const int st = blockIdx.x;   // s-tile 0..15
    const int bh = blockIdx.y;   // 0..31
    const int b = bh >> 3, h = bh & 7;
    const int tid = threadIdx.x;
    const int s0 = st * 64;

#pragma unroll
    for (int i = 0; i < 4; ++i) {
        int idx = tid + 256 * i;     // 0..1023
        int r = idx >> 4;            // row 0..63
        int c4 = (idx & 15) << 2;    // e 0,4..60
        size_t gin = (((size_t)b * Ln + s0 + r) * Hn + h) * En + c4;
        f32x4 qv = *(const f32x4*)(Q + gin);
        f32x4 kv = *(const f32x4*)(K + gin);
        f32x4 vv = *(const f32x4*)(V + gin);
        vlds[r][c4 + 0] = vv.x; vlds[r][c4 + 1] = vv.y;
        vlds[r][c4 + 2] = vv.z; vlds[r][c4 + 3] = vv.w;
        h16x4 qh4, ql4, kh4, kl4;
#pragma unroll
        for (int j = 0; j < 4; ++j) {
            float x = qv[j];
            _Float16 hx = (_Float16)x;
            qh4[j] = hx; ql4[j] = (_Float16)(x - (float)hx);
            float y = kv[j];
            _Float16 hy = (_Float16)y;
            kh4[j] = hy; kl4[j] = (_Float16)(y - (float)hy);
        }
        size_t ob = ((((size_t)bh * 16 + st) * 8 + (c4 >> 3)) * 64 + r) * 8 + (c4 & 7);
        *(h16x4*)(Qh + ob) = qh4; *(h16x4*)(Ql + ob) = ql4;
        *(h16x4*)(Kh + ob) = kh4; *(h16x4*)(Kl + ob) = kl4;
    }
    __syncthreads();
    // transposed V tile, fragment-major: rows = d, k-chunks over local s
#pragma unroll
    for (int i = 0; i < 4; ++i) {
        int idx = tid + 256 * i;
        int d = idx >> 4;            // 0..63
        int sg = (idx & 15) << 2;    // 0..60
        h16x4 v4;
#pragma unroll
        for (int j = 0; j < 4; ++j) v4[j] = (_Float16)vlds[sg + j][d];
        size_t ob = ((((size_t)bh * 16 + st) * 8 + (sg >> 3)) * 64 + d) * 8 + (sg & 7);
        *(h16x4*)(Vt + ob) = v4;
    }
}

// ---------------------------------------------------------------------------
// prep2: batch-independent mask precompute.
//   mh[h][l][s] = 0.125 * sigmoid((log(u+eps)-log(1-u+eps)+phi)/tau) * hard
// ---------------------------------------------------------------------------
__global__ __launch_bounds__(256) void prep2(
    const float* __restrict__ phi, const float* __restrict__ u,
    const float* __restrict__ hard, const float* __restrict__ p_lt,
    _Float16* __restrict__ mh) {
    const float tau = fminf(fmaxf(expf(p_lt[0]), 0.1f), 5.0f);
    const float itau = 1.0f / tau;
    const size_t base = ((size_t)blockIdx.x * 256 + threadIdx.x) * 8;
    const size_t ls = base & (size_t)(Ln * Sn - 1);
    f32x4 ph0 = *(const f32x4*)(phi + base);
    f32x4 ph1 = *(const f32x4*)(phi + base + 4);
    f32x4 uu0 = *(const f32x4*)(u + base);
    f32x4 uu1 = *(const f32x4*)(u + base + 4);
    f32x4 hm0 = *(const f32x4*)(hard + ls);
    f32x4 hm1 = *(const f32x4*)(hard + ls + 4);
    h16x8 o;
#pragma unroll
    for (int j = 0; j < 4; ++j) {
        float z = (__logf((uu0[j] + 1e-8f) * frcp(1.0f - uu0[j] + 1e-8f)) + ph0[j]) * itau;
        float m = frcp(1.0f + __expf(-z));
        o[j] = (_Float16)(0.125f * m * hm0[j]);
    }
#pragma unroll
    for (int j = 0; j < 4; ++j) {
        float z = (__logf((uu1[j] + 1e-8f) * frcp(1.0f - uu1[j] + 1e-8f)) + ph1[j]) * itau;
        float m = frcp(1.0f + __expf(-z));
        o[4 + j] = (_Float16)(0.125f * m * hm1[j]);
    }
    *(h16x8*)(mh + base) = o;
}

// ---------------------------------------------------------------------------
// fused: barrier-free, XCD-pinned. Grid = flat 2048; bijective swizzle
// work = (f&7)*256 + (f>>3) pins head h = XCD (all 4 batches, 16 l-tiles x
// 4 s-quarters). Per-XCD L2 working set: 4 bh x 5 arrays (2.5 MB) + mh[h]
// (2 MB) -> fragments are L2 hits.
// launch_bounds(256,4): VGPR=64 naturally (round-3 codegen) -> HW still fits
// 8 waves/SIMD; (256,8) forced VGPR=32 and spilled to scratch (round 4:
// 3x regression, WRITE 186->608 MB). Do NOT clamp below the live-reg floor.
// Per block: 4 chunks of 64 s; QK f16-split MFMA -> elementwise -> PV MFMA.
// ---------------------------------------------------------------------------
__global__ __launch_bounds__(256, 4) void fused_lie(
    const _Float16* __restrict__ Qh, const _Float16* __restrict__ Ql,
    const _Float16* __restrict__ Kh, const _Float16* __restrict__ Kl,
    const _Float16* __restrict__ Vt, const _Float16* __restrict__ mh,
    const float* __restrict__ p_lg, const float* __restrict__ p_ltc,
    float* __restrict__ Aout, float* __restrict__ Vout,
    float* __restrict__ entOut) {
    __shared__ __align__(16) _Float16 plds[4][16 * 72];

    // ---- XCD-pinned work decode (8 XCDs, flat%8 = XCD assumption) ----
    const int f = blockIdx.x;                 // 0..2047
    const int work = (f & 7) * 256 + (f >> 3);
    const int h = work >> 8;                  // 0..7  == XCD
    const int rem = work & 255;
    const int b = rem >> 6;                   // 0..3
    const int tile = rem & 63;
    const int lt = tile >> 2;                 // 0..15
    const int sq = tile & 3;                  // s-quarter 0..3
    const int bh = b * Hn + h;
    const int tid = threadIdx.x;
    const int w = tid >> 6;
    const int lane = tid & 63;
    const int q = lane >> 4;
    const int n = lane & 15;
    const int l0 = lt * 64;

    const float gain = fminf(fmaxf(expf(p_lg[0]), 1e-3f), 1000.0f);
    const float tauc = fminf(fmaxf(expf(p_ltc[0]), 1e-3f), 10.0f);
    const float c2l = 2.0f * gain / tauc * 1.44269504f;   // exp(c2*x) = exp2(c2l*x)

    // A-side fragments (registers): rows l0+w*16+n, k-chunk q+4*kh
    h16x8 QAh[2], QAl[2], KAh[2], KAl[2];
    {
        const size_t ab = (((size_t)bh * 16 + lt) * 8) * 512 + (size_t)(w * 16 + n) * 8;
#pragma unroll
        for (int kh = 0; kh < 2; ++kh) {
            size_t off = ab + (size_t)(q + 4 * kh) * 512;
            QAh[kh] = *(const h16x8*)(Qh + off);
            QAl[kh] = *(const h16x8*)(Ql + off);
            KAh[kh] = *(const h16x8*)(Kh + off);
            KAl[kh] = *(const h16x8*)(Kl + off);
        }
    }

    f32x4 accV[4];
#pragma unroll
    for (int i = 0; i < 4; ++i) accV[i] = (f32x4){0.f, 0.f, 0.f, 0.f};
    float entp[4] = {0.f, 0.f, 0.f, 0.f};

    const int lbase = l0 + w * 16 + q * 4;
    float* __restrict__ arow = Aout + (((size_t)b * Hn + h) * Ln + lbase) * (size_t)Sn;
    const _Float16* __restrict__ ment = mh + ((size_t)h * Ln + lbase) * (size_t)Sn;

    for (int stc = 0; stc < 4; ++stc) {
        const int st = sq * 4 + stc;
        const int s0 = st * 64;
        const size_t tb = (((size_t)bh * 16 + st) * 8) * 512;

        // ---- QK: acc1 = Q.K^T, acc2 = K.Q^T (f16 split, direct global B) ----
        f32x4 a1[4], a2[4];
#pragma unroll
        for (int i = 0; i < 4; ++i) {
            a1[i] = (f32x4){0.f, 0.f, 0.f, 0.f};
            a2[i] = (f32x4){0.f, 0.f, 0.f, 0.f};
        }
#pragma unroll
        for (int kh = 0; kh < 2; ++kh) {
            const size_t kqb = tb + (size_t)(q + 4 * kh) * 512;
#pragma unroll
            for (int sub = 0; sub < 4; ++sub) {
                const size_t off = kqb + (size_t)(sub * 16 + n) * 8;
                h16x8 KBh = *(const h16x8*)(Kh + off);
                h16x8 KBl = *(const h16x8*)(Kl + off);
                h16x8 QBh = *(const h16x8*)(Qh + off);
                h16x8 QBl = *(const h16x8*)(Ql + off);
                f32x4 x1 = a1[sub], x2 = a2[sub];
                x1 = __builtin_amdgcn_mfma_f32_16x16x32_f16(QAh[kh], KBh, x1, 0, 0, 0);
                x1 = __builtin_amdgcn_mfma_f32_16x16x32_f16(QAh[kh], KBl, x1, 0, 0, 0);
                x1 = __builtin_amdgcn_mfma_f32_16x16x32_f16(QAl[kh], KBh, x1, 0, 0, 0);
                x2 = __builtin_amdgcn_mfma_f32_16x16x32_f16(KAh[kh], QBh, x2, 0, 0, 0);
                x2 = __builtin_amdgcn_mfma_f32_16x16x32_f16(KAh[kh], QBl, x2, 0, 0, 0);
                x2 = __builtin_amdgcn_mfma_f32_16x16x32_f16(KAl[kh], QBh, x2, 0, 0, 0);
                a1[sub] = x1; a2[sub] = x2;
            }
        }

        // ---- elementwise chain (C-layout: row q*4+r, col sub*16+n) ----
#pragma unroll
        for (int sub = 0; sub < 4; ++sub) {
            const int s = s0 + sub * 16 + n;
#pragma unroll
            for (int r = 0; r < 4; ++r) {
                float mhv = (float)ment[(size_t)r * Sn + s];
                float cm = a1[sub][r] - a2[sub][r];
                // tanh(c1*cm) = 1 - 2/(exp2(c2l*cm)+1)
                float x = 1.0f - 2.0f * frcp(fexp2(c2l * cm) + 1.0f);
                // tanh-form gelu: x * sigmoid(1.5957691*(x + 0.044715 x^3))
                float t = x * fmaf(0.044715f * x, x, 1.0f);
                float g = x * frcp(1.0f + fexp2(-2.30221271f * t));
                float att = g * mhv;               // mh carries 0.125*m*hard
                arow[(size_t)r * Sn + s] = att;
                entp[r] += att * flog2(fmaxf(att, 1e-8f));
                plds[w][(q * 4 + r) * 72 + sub * 16 + n] = (_Float16)att;
            }
        }
        asm volatile("" ::: "memory");   // order plds writes before PV reads

        // ---- PV: accV += P . V (P A-frags from per-warp LDS, V^T global) ----
        {
            const _Float16* pw = &plds[w][0];
#pragma unroll
            for (int kh = 0; kh < 2; ++kh) {
                const size_t kqb = tb + (size_t)(q + 4 * kh) * 512;
                h16x8 Pf = *(const h16x8*)&pw[n * 72 + q * 8 + kh * 32];
#pragma unroll
                for (int sub = 0; sub < 4; ++sub) {
                    h16x8 Vf = *(const h16x8*)(Vt + kqb + (size_t)(sub * 16 + n) * 8);
                    accV[sub] = __builtin_amdgcn_mfma_f32_16x16x32_f16(Pf, Vf, accV[sub], 0, 0, 0);
                }
            }
        }
        asm volatile("" ::: "memory");   // order PV reads before next chunk's writes
    }

    // ---- epilogue: V partial sums via atomics (4 s-quarter blocks per l) ----
#pragma unroll
    for (int sub = 0; sub < 4; ++sub) {
#pragma unroll
        for (int r = 0; r < 4; ++r) {
            const int l = l0 + w * 16 + q * 4 + r;
            atomicAdd(Vout + (((size_t)b * Ln + l) * Hn + h) * En + sub * 16 + n, accV[sub][r]);
        }
    }
    // ---- entropy: quad-row reduce over 16 lanes, atomic partial (ln2 scale) ----
#pragma unroll
    for (int r = 0; r < 4; ++r) {
        float v = entp[r];
        v += __shfl_xor(v, 1);
        v += __shfl_xor(v, 2);
        v += __shfl_xor(v, 4);
        v += __shfl_xor(v, 8);
        if (n == 0) {
            atomicAdd(entOut + ((size_t)b * Hn + h) * Ln + lbase + r, -v * 0.69314718f);
        }
    }
}

extern "C" void kernel_launch(void* const* d_in, const int* in_sizes, int n_in,
                              void* d_out, int out_size, void* d_ws, size_t ws_size,
                              hipStream_t stream) {
    (void)in_sizes; (void)n_in; (void)ws_size; (void)out_size;

    const float* Q    = (const float*)d_in[0];   // (B,L,H,E)
    const float* K    = (const float*)d_in[1];   // (B,S,H,E)
    const float* Vv   = (const float*)d_in[2];   // (B,S,H,E)
    const float* phi  = (const float*)d_in[3];   // (H,L,S)
    const float* lg   = (const float*)d_in[4];
    const float* ltau = (const float*)d_in[5];
    const float* ltc  = (const float*)d_in[6];
    const float* hard = (const float*)d_in[7];   // (L,S)
    const float* u    = (const float*)d_in[8];   // (H,L,S)

    float* out  = (float*)d_out;
    float* Vout = out;                                 // B*L*H*E
    float* Aout = out + (size_t)Bn * Ln * Hn * En;     // B*H*L*S
    float* ent  = Aout + (size_t)Bn * Hn * Ln * Sn;    // B*H*L

    const size_t NE = (size_t)32 * 1024 * 64;          // 2.1M halves per array
    _Float16* Qh = (_Float16*)d_ws;
    _Float16* Ql = Qh + NE;
    _Float16* Kh = Ql + NE;
    _Float16* Kl = Kh + NE;
    _Float16* Vt = Kl + NE;
    _Float16* mh = Vt + NE;                            // H*L*S halves (16 MB)

    hipMemsetAsync(Vout, 0, (size_t)Bn * Ln * Hn * En * sizeof(float), stream);
    hipMemsetAsync(ent, 0, (size_t)Bn * Hn * Ln * sizeof(float), stream);
    prep<<<dim3(16, 32), 256, 0, stream>>>(Q, K, Vv, Qh, Ql, Kh, Kl, Vt);
    prep2<<<dim3(4096), 256, 0, stream>>>(phi, u, hard, ltau, mh);
    fused_lie<<<dim3(2048), 256, 0, stream>>>(Qh, Ql, Kh, Kl, Vt, mh,
                                              lg, ltc, Aout, Vout, ent);
}

// Round 6
// 345.159 us; speedup vs baseline: 1.7474x; 1.0606x over previous
//
#include <hip/hip_runtime.h>
#include <math.h>

#define Bn 4
#define Ln 1024
#define Sn 1024
#define Hn 8
#define En 64

typedef __attribute__((ext_vector_type(4))) float f32x4;
typedef __attribute__((ext_vector_type(8))) _Float16 h16x8;
typedef __attribute__((ext_vector_type(4))) _Float16 h16x4;

__device__ __forceinline__ float frcp(float x) { return __builtin_amdgcn_rcpf(x); }
__device__ __forceinline__ float fexp2(float x) {
    float r; asm("v_exp_f32 %0, %1" : "=v"(r) : "v"(x)); return r;
}
__device__ __forceinline__ float flog2(float x) {
    float r; asm("v_log_f32 %0, %1" : "=v"(r) : "v"(x)); return r;
}

// ---------------------------------------------------------------------------
// prep: split Q,K fp32 -> f16 hi/lo, fragment-major layout
//   [bh][tile][kq][row][8]  (kq = 8-half k-chunk 0..7, row 0..63 in tile)
// V -> f16 transposed tiles in the same fragment-major layout (rows = d,
// k-chunks over local s).
// ---------------------------------------------------------------------------
__global__ __launch_bounds__(256) void prep(
    const float* __restrict__ Q, const float* __restrict__ K,
    const float* __restrict__ V,
    _Float16* __restrict__ Qh, _Float16* __restrict__ Ql,
    _Float16* __restrict__ Kh, _Float16* __restrict__ Kl,
    _Float16* __restrict__ Vt) {
    __shared__ float vlds[64][69];
    const int st = blockIdx.x;   // s-tile 0..15
    const int bh = blockIdx.y;   // 0..31
    const int b = bh >> 3, h = bh & 7;
    const int tid = threadIdx.x;
    const int s0 = st * 64;

#pragma unroll
    for (int i = 0; i < 4; ++i) {
        int idx = tid + 256 * i;     // 0..1023
        int r = idx >> 4;            // row 0..63
        int c4 = (idx & 15) << 2;    // e 0,4..60
        size_t gin = (((size_t)b * Ln + s0 + r) * Hn + h) * En + c4;
        f32x4 qv = *(const f32x4*)(Q + gin);
        f32x4 kv = *(const f32x4*)(K + gin);
        f32x4 vv = *(const f32x4*)(V + gin);
        vlds[r][c4 + 0] = vv.x; vlds[r][c4 + 1] = vv.y;
        vlds[r][c4 + 2] = vv.z; vlds[r][c4 + 3] = vv.w;
        h16x4 qh4, ql4, kh4, kl4;
#pragma unroll
        for (int j = 0; j < 4; ++j) {
            float x = qv[j];
            _Float16 hx = (_Float16)x;
            qh4[j] = hx; ql4[j] = (_Float16)(x - (float)hx);
            float y = kv[j];
            _Float16 hy = (_Float16)y;
            kh4[j] = hy; kl4[j] = (_Float16)(y - (float)hy);
        }
        size_t ob = ((((size_t)bh * 16 + st) * 8 + (c4 >> 3)) * 64 + r) * 8 + (c4 & 7);
        *(h16x4*)(Qh + ob) = qh4; *(h16x4*)(Ql + ob) = ql4;
        *(h16x4*)(Kh + ob) = kh4; *(h16x4*)(Kl + ob) = kl4;
    }
    __syncthreads();
    // transposed V tile, fragment-major: rows = d, k-chunks over local s
#pragma unroll
    for (int i = 0; i < 4; ++i) {
        int idx = tid + 256 * i;
        int d = idx >> 4;            // 0..63
        int sg = (idx & 15) << 2;    // 0..60
        h16x4 v4;
#pragma unroll
        for (int j = 0; j < 4; ++j) v4[j] = (_Float16)vlds[sg + j][d];
        size_t ob = ((((size_t)bh * 16 + st) * 8 + (sg >> 3)) * 64 + d) * 8 + (sg & 7);
        *(h16x4*)(Vt + ob) = v4;
    }
}

// ---------------------------------------------------------------------------
// prep2: batch-independent mask precompute.
//   mh[h][l][s] = 0.125 * sigmoid((log(u+eps)-log(1-u+eps)+phi)/tau) * hard
// ---------------------------------------------------------------------------
__global__ __launch_bounds__(256) void prep2(
    const float* __restrict__ phi, const float* __restrict__ u,
    const float* __restrict__ hard, const float* __restrict__ p_lt,
    _Float16* __restrict__ mh) {
    const float tau = fminf(fmaxf(expf(p_lt[0]), 0.1f), 5.0f);
    const float itau = 1.0f / tau;
    const size_t base = ((size_t)blockIdx.x * 256 + threadIdx.x) * 8;
    const size_t ls = base & (size_t)(Ln * Sn - 1);
    f32x4 ph0 = *(const f32x4*)(phi + base);
    f32x4 ph1 = *(const f32x4*)(phi + base + 4);
    f32x4 uu0 = *(const f32x4*)(u + base);
    f32x4 uu1 = *(const f32x4*)(u + base + 4);
    f32x4 hm0 = *(const f32x4*)(hard + ls);
    f32x4 hm1 = *(const f32x4*)(hard + ls + 4);
    h16x8 o;
#pragma unroll
    for (int j = 0; j < 4; ++j) {
        float z = (__logf((uu0[j] + 1e-8f) * frcp(1.0f - uu0[j] + 1e-8f)) + ph0[j]) * itau;
        float m = frcp(1.0f + __expf(-z));
        o[j] = (_Float16)(0.125f * m * hm0[j]);
    }
#pragma unroll
    for (int j = 0; j < 4; ++j) {
        float z = (__logf((uu1[j] + 1e-8f) * frcp(1.0f - uu1[j] + 1e-8f)) + ph1[j]) * itau;
        float m = frcp(1.0f + __expf(-z));
        o[4 + j] = (_Float16)(0.125f * m * hm1[j]);
    }
    *(h16x8*)(mh + base) = o;
}

// ---------------------------------------------------------------------------
// fused: barrier-free, XCD-pinned, streaming A writes.
// Grid = flat 1024; bijective swizzle work = (f&7)*128 + (f>>3) pins head
// h = XCD (4 batches x 16 l-tiles x 2 s-halves). Per-XCD L2 read set:
// 4 bh x 5 arrays (2.5 MB) + mh[h] (2 MB) ~ L2-resident; Aout is written
// NON-TEMPORALLY so the 128 MB stream doesn't evict it (round-5 lesson:
// FETCH stalled at 132 MB with cached stores).
// s-half split (not quarters): halves Vout/ent atomic RMW traffic
// (round 5: quarters cost +32 MB WRITE for no gain).
// launch_bounds(256,4): VGPR=64; (256,8) forced VGPR=32 and spilled 3x
// (round 4). Per block: 8 chunks of 64 s; QK f16-split MFMA -> EW -> PV.
// ---------------------------------------------------------------------------
__global__ __launch_bounds__(256, 4) void fused_lie(
    const _Float16* __restrict__ Qh, const _Float16* __restrict__ Ql,
    const _Float16* __restrict__ Kh, const _Float16* __restrict__ Kl,
    const _Float16* __restrict__ Vt, const _Float16* __restrict__ mh,
    const float* __restrict__ p_lg, const float* __restrict__ p_ltc,
    float* __restrict__ Aout, float* __restrict__ Vout,
    float* __restrict__ entOut) {
    __shared__ __align__(16) _Float16 plds[4][16 * 72];

    // ---- XCD-pinned work decode (8 XCDs, flat%8 = XCD assumption) ----
    const int f = blockIdx.x;                 // 0..1023
    const int work = (f & 7) * 128 + (f >> 3);
    const int h = work >> 7;                  // 0..7  == XCD
    const int rem = work & 127;
    const int b = rem >> 5;                   // 0..3
    const int tile = rem & 31;
    const int lt = tile >> 1;                 // 0..15
    const int sh = tile & 1;                  // s-half 0..1
    const int bh = b * Hn + h;
    const int tid = threadIdx.x;
    const int w = tid >> 6;
    const int lane = tid & 63;
    const int q = lane >> 4;
    const int n = lane & 15;
    const int l0 = lt * 64;

    const float gain = fminf(fmaxf(expf(p_lg[0]), 1e-3f), 1000.0f);
    const float tauc = fminf(fmaxf(expf(p_ltc[0]), 1e-3f), 10.0f);
    const float c2l = 2.0f * gain / tauc * 1.44269504f;   // exp(c2*x) = exp2(c2l*x)

    // A-side fragments (registers): rows l0+w*16+n, k-chunk q+4*kh
    h16x8 QAh[2], QAl[2], KAh[2], KAl[2];
    {
        const size_t ab = (((size_t)bh * 16 + lt) * 8) * 512 + (size_t)(w * 16 + n) * 8;
#pragma unroll
        for (int kh = 0; kh < 2; ++kh) {
            size_t off = ab + (size_t)(q + 4 * kh) * 512;
            QAh[kh] = *(const h16x8*)(Qh + off);
            QAl[kh] = *(const h16x8*)(Ql + off);
            KAh[kh] = *(const h16x8*)(Kh + off);
            KAl[kh] = *(const h16x8*)(Kl + off);
        }
    }

    f32x4 accV[4];
#pragma unroll
    for (int i = 0; i < 4; ++i) accV[i] = (f32x4){0.f, 0.f, 0.f, 0.f};
    float entp[4] = {0.f, 0.f, 0.f, 0.f};

    const int lbase = l0 + w * 16 + q * 4;
    float* __restrict__ arow = Aout + (((size_t)b * Hn + h) * Ln + lbase) * (size_t)Sn;
    const _Float16* __restrict__ ment = mh + ((size_t)h * Ln + lbase) * (size_t)Sn;

    for (int stc = 0; stc < 8; ++stc) {
        const int st = sh * 8 + stc;
        const int s0 = st * 64;
        const size_t tb = (((size_t)bh * 16 + st) * 8) * 512;

        // ---- QK: acc1 = Q.K^T, acc2 = K.Q^T (f16 split, direct global B) ----
        f32x4 a1[4], a2[4];
#pragma unroll
        for (int i = 0; i < 4; ++i) {
            a1[i] = (f32x4){0.f, 0.f, 0.f, 0.f};
            a2[i] = (f32x4){0.f, 0.f, 0.f, 0.f};
        }
#pragma unroll
        for (int kh = 0; kh < 2; ++kh) {
            const size_t kqb = tb + (size_t)(q + 4 * kh) * 512;
#pragma unroll
            for (int sub = 0; sub < 4; ++sub) {
                const size_t off = kqb + (size_t)(sub * 16 + n) * 8;
                h16x8 KBh = *(const h16x8*)(Kh + off);
                h16x8 KBl = *(const h16x8*)(Kl + off);
                h16x8 QBh = *(const h16x8*)(Qh + off);
                h16x8 QBl = *(const h16x8*)(Ql + off);
                f32x4 x1 = a1[sub], x2 = a2[sub];
                x1 = __builtin_amdgcn_mfma_f32_16x16x32_f16(QAh[kh], KBh, x1, 0, 0, 0);
                x1 = __builtin_amdgcn_mfma_f32_16x16x32_f16(QAh[kh], KBl, x1, 0, 0, 0);
                x1 = __builtin_amdgcn_mfma_f32_16x16x32_f16(QAl[kh], KBh, x1, 0, 0, 0);
                x2 = __builtin_amdgcn_mfma_f32_16x16x32_f16(KAh[kh], QBh, x2, 0, 0, 0);
                x2 = __builtin_amdgcn_mfma_f32_16x16x32_f16(KAh[kh], QBl, x2, 0, 0, 0);
                x2 = __builtin_amdgcn_mfma_f32_16x16x32_f16(KAl[kh], QBh, x2, 0, 0, 0);
                a1[sub] = x1; a2[sub] = x2;
            }
        }

        // ---- elementwise chain (C-layout: row q*4+r, col sub*16+n) ----
#pragma unroll
        for (int sub = 0; sub < 4; ++sub) {
            const int s = s0 + sub * 16 + n;
#pragma unroll
            for (int r = 0; r < 4; ++r) {
                float mhv = (float)ment[(size_t)r * Sn + s];
                float cm = a1[sub][r] - a2[sub][r];
                // tanh(c1*cm) = 1 - 2/(exp2(c2l*cm)+1)
                float x = 1.0f - 2.0f * frcp(fexp2(c2l * cm) + 1.0f);
                // tanh-form gelu: x * sigmoid(1.5957691*(x + 0.044715 x^3))
                float t = x * fmaf(0.044715f * x, x, 1.0f);
                float g = x * frcp(1.0f + fexp2(-2.30221271f * t));
                float att = g * mhv;               // mh carries 0.125*m*hard
                __builtin_nontemporal_store(att, &arow[(size_t)r * Sn + s]);
                entp[r] += att * flog2(fmaxf(att, 1e-8f));
                plds[w][(q * 4 + r) * 72 + sub * 16 + n] = (_Float16)att;
            }
        }
        asm volatile("" ::: "memory");   // order plds writes before PV reads

        // ---- PV: accV += P . V (P A-frags from per-warp LDS, V^T global) ----
        {
            const _Float16* pw = &plds[w][0];
#pragma unroll
            for (int kh = 0; kh < 2; ++kh) {
                const size_t kqb = tb + (size_t)(q + 4 * kh) * 512;
                h16x8 Pf = *(const h16x8*)&pw[n * 72 + q * 8 + kh * 32];
#pragma unroll
                for (int sub = 0; sub < 4; ++sub) {
                    h16x8 Vf = *(const h16x8*)(Vt + kqb + (size_t)(sub * 16 + n) * 8);
                    accV[sub] = __builtin_amdgcn_mfma_f32_16x16x32_f16(Pf, Vf, accV[sub], 0, 0, 0);
                }
            }
        }
        asm volatile("" ::: "memory");   // order PV reads before next chunk's writes
    }

    // ---- epilogue: V partial sums via atomics (2 s-half blocks per l) ----
#pragma unroll
    for (int sub = 0; sub < 4; ++sub) {
#pragma unroll
        for (int r = 0; r < 4; ++r) {
            const int l = l0 + w * 16 + q * 4 + r;
            atomicAdd(Vout + (((size_t)b * Ln + l) * Hn + h) * En + sub * 16 + n, accV[sub][r]);
        }
    }
    // ---- entropy: quad-row reduce over 16 lanes, atomic partial (ln2 scale) ----
#pragma unroll
    for (int r = 0; r < 4; ++r) {
        float v = entp[r];
        v += __shfl_xor(v, 1);
        v += __shfl_xor(v, 2);
        v += __shfl_xor(v, 4);
        v += __shfl_xor(v, 8);
        if (n == 0) {
            atomicAdd(entOut + ((size_t)b * Hn + h) * Ln + lbase + r, -v * 0.69314718f);
        }
    }
}

extern "C" void kernel_launch(void* const* d_in, const int* in_sizes, int n_in,
                              void* d_out, int out_size, void* d_ws, size_t ws_size,
                              hipStream_t stream) {
    (void)in_sizes; (void)n_in; (void)ws_size; (void)out_size;

    const float* Q    = (const float*)d_in[0];   // (B,L,H,E)
    const float* K    = (const float*)d_in[1];   // (B,S,H,E)
    const float* Vv   = (const float*)d_in[2];   // (B,S,H,E)
    const float* phi  = (const float*)d_in[3];   // (H,L,S)
    const float* lg   = (const float*)d_in[4];
    const float* ltau = (const float*)d_in[5];
    const float* ltc  = (const float*)d_in[6];
    const float* hard = (const float*)d_in[7];   // (L,S)
    const float* u    = (const float*)d_in[8];   // (H,L,S)

    float* out  = (float*)d_out;
    float* Vout = out;                                 // B*L*H*E
    float* Aout = out + (size_t)Bn * Ln * Hn * En;     // B*H*L*S
    float* ent  = Aout + (size_t)Bn * Hn * Ln * Sn;    // B*H*L

    const size_t NE = (size_t)32 * 1024 * 64;          // 2.1M halves per array
    _Float16* Qh = (_Float16*)d_ws;
    _Float16* Ql = Qh + NE;
    _Float16* Kh = Ql + NE;
    _Float16* Kl = Kh + NE;
    _Float16* Vt = Kl + NE;
    _Float16* mh = Vt + NE;                            // H*L*S halves (16 MB)

    hipMemsetAsync(Vout, 0, (size_t)Bn * Ln * Hn * En * sizeof(float), stream);
    hipMemsetAsync(ent, 0, (size_t)Bn * Hn * Ln * sizeof(float), stream);
    prep<<<dim3(16, 32), 256, 0, stream>>>(Q, K, Vv, Qh, Ql, Kh, Kl, Vt);
    prep2<<<dim3(4096), 256, 0, stream>>>(phi, u, hard, ltau, mh);
    fused_lie<<<dim3(1024), 256, 0, stream>>>(Qh, Ql, Kh, Kl, Vt, mh,
                                              lg, ltc, Aout, Vout, ent);
}